// Round 4
// baseline (80.763 us; speedup 1.0000x reference)
//
#include <hip/hip_runtime.h>

// (B,N,M,K) = (4,512,512,256): out[2048,256] = xq[2048,512] · wq[256,512]^T (int8)
// Fully fused: quantize-in-registers -> mfma_i32_16x16x64_i8, one dispatch,
// no workspace, no LDS, no barriers. lut[xi,wi] == signed(xi)*signed(wi).
// Zero-point sums via all-ones MFMA fragments (exact int32, layout-matched).
constexpr int Mdim = 512;
constexpr int Kdim = 256;
constexpr int ROWS = 2048;

typedef int v4i __attribute__((ext_vector_type(4)));

__device__ __forceinline__ int qz(float v, float inv, float zp) {
    float q = rintf(fmaf(v, inv, zp));        // round-half-even, matches jnp.round
    q = fminf(fmaxf(q, -128.0f), 127.0f);
    return (int)q;
}

__device__ __forceinline__ int qpack4(float4 f, float inv, float zp) {
    int q0 = qz(f.x, inv, zp), q1 = qz(f.y, inv, zp);
    int q2 = qz(f.z, inv, zp), q3 = qz(f.w, inv, zp);
    return (q0 & 255) | ((q1 & 255) << 8) | ((q2 & 255) << 16) | ((q3 & 255) << 24);
}

// Quantize 16 consecutive floats (64B-aligned) into one int8x16 MFMA fragment reg.
__device__ __forceinline__ v4i quant16(const float* __restrict__ p, float inv, float zp) {
    const float4* p4 = (const float4*)p;
    float4 f0 = p4[0], f1 = p4[1], f2 = p4[2], f3 = p4[3];
    v4i r;
    r[0] = qpack4(f0, inv, zp);
    r[1] = qpack4(f1, inv, zp);
    r[2] = qpack4(f2, inv, zp);
    r[3] = qpack4(f3, inv, zp);
    return r;
}

// 512 blocks x 256 threads; wave wv of block handles tile = bid*4+wv.
// Tile (rt,ct): rt = tile>>4, ct = tile&15 -> 16x16 output at (rt*16, ct*16).
// A frag (HW-verified R3): lane l holds X[r0+(l&15)][k-bytes kk*64+(l>>4)*16 ..+16)
// B frag: lane l holds W[c0+(l&15)][same bytes]  (row-major W == W^T columns)
// D: col = c0+(l&15), row = r0+(l>>4)*4+reg
__global__ __launch_bounds__(256) void fused_lutgemm_kernel(
        const float* __restrict__ x, const float* __restrict__ w,
        const float* __restrict__ x_scale, const float* __restrict__ x_zp,
        const float* __restrict__ w_scale, const float* __restrict__ w_zp,
        float* __restrict__ out) {
    const int lane  = threadIdx.x & 63;
    const int wv    = threadIdx.x >> 6;
    const int tile  = blockIdx.x * 4 + wv;
    const int r0    = (tile >> 4) * 16;
    const int c0    = (tile & 15) * 16;
    const int lo    = lane & 15;
    const int group = lane >> 4;

    const float xs  = x_scale[0], xzp = x_zp[0];
    const float wsf = w_scale[0], wzp = w_zp[0];
    const float xinv = 1.0f / xs;             // uniform, computed once
    const float winv = 1.0f / wsf;

    const float* xrow = x + (size_t)(r0 + lo) * Mdim;
    const float* wrow = w + (size_t)(c0 + lo) * Mdim;

    v4i acc  = {0, 0, 0, 0};                  // x·w^T
    v4i accx = {0, 0, 0, 0};                  // xsum per row (B = ones)
    v4i accw = {0, 0, 0, 0};                  // wsum per col (A = ones)
    const v4i ones = {0x01010101, 0x01010101, 0x01010101, 0x01010101};

    #pragma unroll
    for (int kk = 0; kk < 8; ++kk) {
        const int off = kk * 64 + group * 16; // float (== int8-k) offset, 64B aligned
        v4i a = quant16(xrow + off, xinv, xzp);
        v4i b = quant16(wrow + off, winv, wzp);
        acc  = __builtin_amdgcn_mfma_i32_16x16x64_i8(a, b,    acc,  0, 0, 0);
        accx = __builtin_amdgcn_mfma_i32_16x16x64_i8(a, ones, accx, 0, 0, 0);
        accw = __builtin_amdgcn_mfma_i32_16x16x64_i8(ones, b, accw, 0, 0, 0);
    }

    // ref: (acc - wzp*xsum_row - xzp*wsum_col + M*xzp*wzp) * xs*ws
    const float corr = (float)Mdim * xzp * wzp;
    const float osc  = xs * wsf;
    #pragma unroll
    for (int i = 0; i < 4; ++i) {
        const int row = r0 + group * 4 + i;
        float v = (float)acc[i] - wzp * (float)accx[i] - xzp * (float)accw[i] + corr;
        out[(size_t)row * Kdim + c0 + lo] = v * osc;  // 16-lane contiguous stores
    }
}

extern "C" void kernel_launch(void* const* d_in, const int* in_sizes, int n_in,
                              void* d_out, int out_size, void* d_ws, size_t ws_size,
                              hipStream_t stream) {
    const float* x       = (const float*)d_in[0];
    const float* w       = (const float*)d_in[1];
    // d_in[2] = lut: unused (lut[xi,wi] == signed(xi)*signed(wi))
    const float* x_scale = (const float*)d_in[3];
    const float* x_zp    = (const float*)d_in[4];
    const float* w_scale = (const float*)d_in[5];
    const float* w_zp    = (const float*)d_in[6];
    float* out = (float*)d_out;
    (void)d_ws; (void)ws_size;

    fused_lutgemm_kernel<<<(ROWS / 16) * (Kdim / 16) / 4, 256, 0, stream>>>(
        x, w, x_scale, x_zp, w_scale, w_zp, out);
}

// Round 5
// 72.625 us; speedup vs baseline: 1.1121x; 1.1121x over previous
//
#include <hip/hip_runtime.h>

// (B,N,M,K) = (4,512,512,256): out[2048,256] = xq[2048,512] · wq[256,512]^T (int8)
// R3 structure (best measured: 72.8 us): quantize once to ws, then MFMA gemm.
// R5 tweak: each gemm wave does a 16x32 tile (2 col-tiles share A frags).
constexpr int Mdim = 512;
constexpr int Kdim = 256;
constexpr int ROWS = 2048;
constexpr int MW   = Mdim / 4;   // 128 packed int8-words per row

// ws layout (ints):
constexpr int XQ_OFF   = 0;                      // 2048 x 128 words, row-major
constexpr int WQ_OFF   = ROWS * MW;              // 262144: 256 x 128 words, row-major
constexpr int XSUM_OFF = WQ_OFF + Kdim * MW;     // 294912
constexpr int WSUM_OFF = XSUM_OFF + ROWS;        // 296960

typedef int v4i __attribute__((ext_vector_type(4)));

__device__ __forceinline__ int qz(float v, float scale, float zp) {
    float q = rintf(v / scale + zp);          // matches jnp.round(t/scale + zp)
    q = fminf(fmaxf(q, -128.0f), 127.0f);
    return (int)q;
}

__device__ __forceinline__ int pack4(int q0, int q1, int q2, int q3) {
    return (q0 & 255) | ((q1 & 255) << 8) | ((q2 & 255) << 16) | ((q3 & 255) << 24);
}

// Blocks [0,2048): x rows; [2048,2304): w rows. One wave/row, 8 floats/thread.
__global__ __launch_bounds__(64) void quant_kernel(
        const float* __restrict__ x, const float* __restrict__ w,
        const float* __restrict__ x_scale, const float* __restrict__ x_zp,
        const float* __restrict__ w_scale, const float* __restrict__ w_zp,
        int* __restrict__ ws) {
    const int tid = threadIdx.x;
    const bool is_x = (blockIdx.x < ROWS);
    const int row = is_x ? blockIdx.x : (blockIdx.x - ROWS);
    const float s  = is_x ? x_scale[0] : w_scale[0];
    const float zp = is_x ? x_zp[0]    : w_zp[0];
    const float* src = (is_x ? x : w) + (size_t)row * Mdim;

    const float4* src4 = (const float4*)src;
    float4 a = src4[tid * 2];
    float4 b = src4[tid * 2 + 1];

    int q0 = qz(a.x, s, zp), q1 = qz(a.y, s, zp), q2 = qz(a.z, s, zp), q3 = qz(a.w, s, zp);
    int q4 = qz(b.x, s, zp), q5 = qz(b.y, s, zp), q6 = qz(b.z, s, zp), q7 = qz(b.w, s, zp);

    const int base = (is_x ? XQ_OFF : WQ_OFF) + row * MW + 2 * tid;
    *(int2*)&ws[base] = make_int2(pack4(q0, q1, q2, q3), pack4(q4, q5, q6, q7));

    int sum = q0 + q1 + q2 + q3 + q4 + q5 + q6 + q7;
    #pragma unroll
    for (int off = 32; off > 0; off >>= 1) sum += __shfl_down(sum, off);
    if (tid == 0) ws[(is_x ? XSUM_OFF : WSUM_OFF) + row] = sum;
}

// One wave per 16x32 output tile. 1024 blocks x 64 threads.
// A frag (HW-verified): lane l holds xq[r0+(l&15)][bytes kk*64+(l>>4)*16 ..+16)
// B frags: lane l holds wq[c+(l&15)][same bytes] for c = c0, c0+16
// D: col = c+(l&15), row = r0+(l>>4)*4+reg
__global__ __launch_bounds__(64) void mfma_gemm_kernel(
        const int* __restrict__ ws,
        const float* __restrict__ x_scale, const float* __restrict__ x_zp,
        const float* __restrict__ w_scale, const float* __restrict__ w_zp,
        float* __restrict__ out) {
    const int lane  = threadIdx.x;
    const int group = lane >> 4;
    const int lo    = lane & 15;
    const int r0 = (blockIdx.x >> 3) * 16;   // 128 row-tiles
    const int c0 = (blockIdx.x & 7) * 32;    // 8 col-pair-tiles

    const v4i* xa  = (const v4i*)&ws[XQ_OFF + (size_t)(r0 + lo) * MW];
    const v4i* wb0 = (const v4i*)&ws[WQ_OFF + (size_t)(c0 + lo) * MW];
    const v4i* wb1 = (const v4i*)&ws[WQ_OFF + (size_t)(c0 + 16 + lo) * MW];

    v4i a[8], b0[8], b1[8];
    #pragma unroll
    for (int kk = 0; kk < 8; ++kk) {         // 24 int4 loads in flight
        a[kk]  = xa[kk * 4 + group];
        b0[kk] = wb0[kk * 4 + group];
        b1[kk] = wb1[kk * 4 + group];
    }

    v4i acc0 = {0, 0, 0, 0};
    v4i acc1 = {0, 0, 0, 0};
    #pragma unroll
    for (int kk = 0; kk < 8; ++kk) {
        acc0 = __builtin_amdgcn_mfma_i32_16x16x64_i8(a[kk], b0[kk], acc0, 0, 0, 0);
        acc1 = __builtin_amdgcn_mfma_i32_16x16x64_i8(a[kk], b1[kk], acc1, 0, 0, 0);
    }

    const float xs = x_scale[0], xzpf = x_zp[0];
    const float wsf = w_scale[0], wzpf = w_zp[0];
    const float oscale = xs * wsf;
    const float base_corr = (float)Mdim * xzpf * wzpf;
    const float wsum0 = (float)ws[WSUM_OFF + c0 + lo];
    const float wsum1 = (float)ws[WSUM_OFF + c0 + 16 + lo];
    const float corr0 = base_corr - xzpf * wsum0;
    const float corr1 = base_corr - xzpf * wsum1;
    const v4i xs4 = *(const v4i*)&ws[XSUM_OFF + r0 + group * 4];  // 16B-aligned

    #pragma unroll
    for (int i = 0; i < 4; ++i) {
        const int row = r0 + group * 4 + i;
        const float xc = wzpf * (float)xs4[i];
        float v0 = (float)acc0[i] - xc + corr0;
        float v1 = (float)acc1[i] - xc + corr1;
        out[(size_t)row * Kdim + c0 + lo]      = v0 * oscale;
        out[(size_t)row * Kdim + c0 + 16 + lo] = v1 * oscale;
    }
}

extern "C" void kernel_launch(void* const* d_in, const int* in_sizes, int n_in,
                              void* d_out, int out_size, void* d_ws, size_t ws_size,
                              hipStream_t stream) {
    const float* x       = (const float*)d_in[0];
    const float* w       = (const float*)d_in[1];
    // d_in[2] = lut: unused (lut[xi,wi] == signed(xi)*signed(wi))
    const float* x_scale = (const float*)d_in[3];
    const float* x_zp    = (const float*)d_in[4];
    const float* w_scale = (const float*)d_in[5];
    const float* w_zp    = (const float*)d_in[6];
    float* out = (float*)d_out;
    int* ws = (int*)d_ws;

    quant_kernel<<<ROWS + Kdim, 64, 0, stream>>>(x, w, x_scale, x_zp, w_scale, w_zp, ws);
    mfma_gemm_kernel<<<(ROWS / 16) * (Kdim / 32), 64, 0, stream>>>(
        ws, x_scale, x_zp, w_scale, w_zp, out);
}